// Round 16
// baseline (1361.492 us; speedup 1.0000x reference)
//
#include <hip/hip_runtime.h>
#include <cstdint>
#include <cstddef>

#define NB 32
#define NN 2048
#define ND 512
#define NH 512
#define NC 512
#define ROWS (NB*NN)                 // 65536

typedef __attribute__((ext_vector_type(8))) short short8v;   // 8 bf16 (4 VGPR)
typedef __attribute__((ext_vector_type(4))) float f32x4;

#define MFMA16(a,b,c) __builtin_amdgcn_mfma_f32_16x16x32_bf16((a),(b),(c),0,0,0)

typedef const __attribute__((address_space(1))) unsigned int* gas_t;
typedef __attribute__((address_space(3))) unsigned int* las_t;

__device__ __forceinline__ void gload16(const void* g, void* l){
  __builtin_amdgcn_global_load_lds((gas_t)g, (las_t)l, 16, 0, 0);
}

// f32 -> bf16 hi/lo split (RNE both).  v ~= h + l, |v-h-l| <= 2^-18 |v|
__device__ __forceinline__ void fsplit(float v, unsigned short& h, unsigned short& l){
  unsigned u = __float_as_uint(v);
  unsigned hb = (u + 0x7FFFu + ((u>>16)&1u)) >> 16;
  float hf = __uint_as_float(hb<<16);
  float r = v - hf;
  unsigned ur = __float_as_uint(r);
  l = (unsigned short)((ur + 0x7FFFu + ((ur>>16)&1u)) >> 16);
  h = (unsigned short)hb;
}

// ---------------- threefry2x32-20 (JAX partitionable scheme) ----------------
__device__ __forceinline__ unsigned rotl32(unsigned x, int d){ return (x<<d)|(x>>(32-d)); }

__device__ __forceinline__ unsigned threefry_xor(unsigned k0, unsigned k1, unsigned c0, unsigned c1){
  unsigned ks2 = 0x1BD11BDAu ^ k0 ^ k1;
  unsigned x0 = c0 + k0, x1 = c1 + k1;
#define TF_RND(r) { x0 += x1; x1 = rotl32(x1,(r)); x1 ^= x0; }
  TF_RND(13) TF_RND(15) TF_RND(26) TF_RND(6)
  x0 += k1;  x1 += ks2 + 1u;
  TF_RND(17) TF_RND(29) TF_RND(16) TF_RND(24)
  x0 += ks2; x1 += k0 + 2u;
  TF_RND(13) TF_RND(15) TF_RND(26) TF_RND(6)
  x0 += k0;  x1 += k1 + 3u;
  TF_RND(17) TF_RND(29) TF_RND(16) TF_RND(24)
  x0 += k1;  x1 += ks2 + 4u;
  TF_RND(13) TF_RND(15) TF_RND(26) TF_RND(6)
  x0 += ks2; x1 += k0 + 5u;
#undef TF_RND
  return x0 ^ x1;
}

__device__ __forceinline__ float bits_to_normal(unsigned bits){
  float f = __uint_as_float((bits >> 9) | 0x3f800000u) - 1.0f;
  const float lo = -0.99999994f;
  float u = fmaxf(lo, fmaf(f, 2.0f, lo));
  float w = -log1pf(-(u*u));
  float p;
  if (w < 5.0f){
    w -= 2.5f;
    p =            2.81022636e-08f;
    p = fmaf(p, w, 3.43273939e-07f);
    p = fmaf(p, w, -3.5233877e-06f);
    p = fmaf(p, w, -4.39150654e-06f);
    p = fmaf(p, w, 0.00021858087f);
    p = fmaf(p, w, -0.00125372503f);
    p = fmaf(p, w, -0.00417768164f);
    p = fmaf(p, w, 0.246640727f);
    p = fmaf(p, w, 1.50140941f);
  } else {
    w = sqrtf(w) - 3.0f;
    p =            -0.000200214257f;
    p = fmaf(p, w, 0.000100950558f);
    p = fmaf(p, w, 0.00134934322f);
    p = fmaf(p, w, -0.00367342844f);
    p = fmaf(p, w, 0.00573950773f);
    p = fmaf(p, w, -0.0076224613f);
    p = fmaf(p, w, 0.00943887047f);
    p = fmaf(p, w, 1.00167406f);
    p = fmaf(p, w, 2.83297682f);
  }
  return 1.4142135623730951f * (p * u);
}

// ---------------- cluster counts + lens ----------------
__global__ void __launch_bounds__(256) counts_kernel(const unsigned char* __restrict__ mraw,
                                                     int* __restrict__ cnum,
                                                     int* __restrict__ lenbuf){
  __shared__ int red[256];
  int b = blockIdx.x, tid = threadIdx.x;
  unsigned char b0 = mraw[0], b1 = mraw[1];
  int cnt = 0;
  if (b0 == 1 && b1 == 1){
    const unsigned char* p = mraw + (size_t)b * NN;
    for (int i = tid; i < NN; i += 256) cnt += (p[i] != 0);
  } else if (b0 == 1){
    const int* p = (const int*)mraw + (size_t)b * NN;
    for (int i = tid; i < NN; i += 256) cnt += (p[i] != 0);
  } else {
    const float* p = (const float*)mraw + (size_t)b * NN;
    for (int i = tid; i < NN; i += 256) cnt += (p[i] != 0.0f);
  }
  red[tid] = cnt; __syncthreads();
  for (int off = 128; off; off >>= 1){ if (tid < off) red[tid] += red[tid+off]; __syncthreads(); }
  if (tid == 0){ cnum[b] = red[0] >> 2; lenbuf[b] = red[0]; }
}

// ---------------- y = adj @ x (adj in {0,1}), wave-scan compaction ----------------
__global__ void __launch_bounds__(256) spmm_kernel(const float* __restrict__ adj,
                                                   const float* __restrict__ x,
                                                   unsigned short* __restrict__ yh,
                                                   unsigned short* __restrict__ yl,
                                                   const int* __restrict__ lenbuf){
  __shared__ int idxs[NN];
  __shared__ int wtot[4];
  int row = blockIdx.x;
  int b = row >> 11;
  int n = row & 2047;
  int tid = threadIdx.x;
  int l = tid & 63, w = tid >> 6;
  size_t base = (size_t)row * ND;
  if (n >= lenbuf[b]){      // adj row all-zero: y = 0 (skip 8KB adj read)
    yh[base+tid]=0; yl[base+tid]=0; yh[base+tid+256]=0; yl[base+tid+256]=0;
    return;
  }
  const float* arow = adj + (size_t)row * NN;
  float v[8];
  *(float4*)&v[0] = *(const float4*)(arow + tid*8);
  *(float4*)&v[4] = *(const float4*)(arow + tid*8 + 4);
  int lc = 0;
  #pragma unroll
  for (int j=0;j<8;j++) lc += (v[j] != 0.0f);
  // wave-level inclusive scan (no barriers), then 1-barrier cross-wave combine
  int sc = lc;
  #pragma unroll
  for (int off=1; off<64; off<<=1){
    int t = __shfl_up(sc, off, 64);
    if (l >= off) sc += t;
  }
  if (l == 63) wtot[w] = sc;
  __syncthreads();
  int basep = 0;
  #pragma unroll
  for (int i=0;i<4;i++) if (i < w) basep += wtot[i];
  int total = wtot[0]+wtot[1]+wtot[2]+wtot[3];
  int pos = basep + sc - lc;
  #pragma unroll
  for (int j=0;j<8;j++){
    if (v[j] != 0.0f){ idxs[pos++] = tid*8 + j; }
  }
  __syncthreads();
  float acc0 = 0.f, acc1 = 0.f;
  const float* xb = x + (size_t)b * NN * ND;
  int j = 0;
  for (; j+4 <= total; j += 4){
    int m0_=idxs[j], m1_=idxs[j+1], m2_=idxs[j+2], m3_=idxs[j+3];
    float a0 = xb[(size_t)m0_*ND + tid], a1 = xb[(size_t)m1_*ND + tid];
    float a2 = xb[(size_t)m2_*ND + tid], a3 = xb[(size_t)m3_*ND + tid];
    float b0 = xb[(size_t)m0_*ND + tid + 256], b1 = xb[(size_t)m1_*ND + tid + 256];
    float b2 = xb[(size_t)m2_*ND + tid + 256], b3 = xb[(size_t)m3_*ND + tid + 256];
    acc0 += a0; acc0 += a1; acc0 += a2; acc0 += a3;
    acc1 += b0; acc1 += b1; acc1 += b2; acc1 += b3;
  }
  for (; j < total; j++){
    int m_ = idxs[j];
    acc0 += xb[(size_t)m_*ND + tid];
    acc1 += xb[(size_t)m_*ND + tid + 256];
  }
  unsigned short h,lo;
  fsplit(acc0,h,lo); yh[base+tid]=h;     yl[base+tid]=lo;
  fsplit(acc1,h,lo); yh[base+tid+256]=h; yl[base+tid+256]=lo;
}

// ---------------- W transpose + split: WT[h][d] ----------------
__global__ void __launch_bounds__(256) wsplit_kernel(const float* __restrict__ W,
                                                     unsigned short* __restrict__ WTh,
                                                     unsigned short* __restrict__ WTl){
  __shared__ float t[32][33];
  int bx = blockIdx.x, by = blockIdx.y;
  int x = threadIdx.x & 31, y = threadIdx.x >> 5;
  for (int yy=y; yy<32; yy+=8) t[yy][x] = W[(size_t)(bx*32+yy)*512 + by*32 + x];
  __syncthreads();
  for (int yy=y; yy<32; yy+=8){
    float v = t[x][yy];                     // = W[bx*32+x][by*32+yy]
    unsigned short h,l; fsplit(v,h,l);
    size_t idx = (size_t)(by*32+yy)*512 + bx*32 + x;
    WTh[idx]=h; WTl[idx]=l;
  }
}

// ---------------- fused rng + masked softmax #1 (split planes only) ----------
__global__ void __launch_bounds__(256) rngsm_kernel(unsigned short* __restrict__ sh,
                                                    unsigned short* __restrict__ sl,
                                                    const int* __restrict__ cnum){
  int row  = blockIdx.x*4 + (threadIdx.x >> 6);
  int lane = threadIdx.x & 63;
  int Kc = cnum[row >> 11];
  float e[8];
  #pragma unroll
  for (int j=0;j<8;j++){
    int c = (j<4) ? lane*4 + j : lane*4 + 252 + j;
    e[j] = bits_to_normal(threefry_xor(0u, 42u, 0u, (unsigned)row*512u + (unsigned)c));
  }
  float m = -3.0e38f;
  #pragma unroll
  for (int j=0;j<8;j++){
    int c = (j<4) ? lane*4 + j : lane*4 + 252 + j;
    if (c < Kc) m = fmaxf(m, e[j]);
  }
  #pragma unroll
  for (int off=32; off; off>>=1) m = fmaxf(m, __shfl_xor(m, off, 64));
  float r[8]; float sum = 0.f;
  #pragma unroll
  for (int j=0;j<8;j++){
    int c = (j<4) ? lane*4 + j : lane*4 + 252 + j;
    r[j] = (c < Kc) ? expf(e[j] - m) : 0.0f;
    sum += r[j];
  }
  #pragma unroll
  for (int off=32; off; off>>=1) sum += __shfl_xor(sum, off, 64);
  float inv = 1.0f / sum;
  #pragma unroll
  for (int j=0;j<8;j++) r[j] *= inv;
  unsigned long long ph=0, pl=0, qh=0, ql=0;
  #pragma unroll
  for (int j=0;j<4;j++){
    unsigned short h,l;
    fsplit(r[j],h,l);
    ph |= (unsigned long long)h << (16*j);  pl |= (unsigned long long)l << (16*j);
    fsplit(r[4+j],h,l);
    qh |= (unsigned long long)h << (16*j);  ql |= (unsigned long long)l << (16*j);
  }
  size_t base = (size_t)row * NC + lane*4;
  *(unsigned long long*)(sh + base)       = ph;
  *(unsigned long long*)(sl + base)       = pl;
  *(unsigned long long*)(sh + base + 256) = qh;
  *(unsigned long long*)(sl + base + 256) = ql;
}

// ---------------- masked softmax ----------------
template<bool SPLIT, bool WF32>
__global__ void __launch_bounds__(256) softmax_kernel(float* __restrict__ s,
                                                      unsigned short* __restrict__ sh,
                                                      unsigned short* __restrict__ sl,
                                                      const int* __restrict__ cnum){
  int row  = blockIdx.x*4 + (threadIdx.x >> 6);
  int lane = threadIdx.x & 63;
  int b = row >> 11;
  int Kc = cnum[b];
  float* p = s + (size_t)row * NC;
  float4 v0 = *(const float4*)(p + lane*4);
  float4 v1 = *(const float4*)(p + lane*4 + 256);
  float e[8] = {v0.x,v0.y,v0.z,v0.w,v1.x,v1.y,v1.z,v1.w};
  float m = -3.0e38f;
  #pragma unroll
  for (int j=0;j<8;j++){
    int c = (j<4) ? lane*4 + j : lane*4 + 252 + j;
    if (c < Kc) m = fmaxf(m, e[j]);
  }
  #pragma unroll
  for (int off=32; off; off>>=1) m = fmaxf(m, __shfl_xor(m, off, 64));
  float r[8]; float sum = 0.f;
  #pragma unroll
  for (int j=0;j<8;j++){
    int c = (j<4) ? lane*4 + j : lane*4 + 252 + j;
    r[j] = (c < Kc) ? expf(e[j] - m) : 0.0f;
    sum += r[j];
  }
  #pragma unroll
  for (int off=32; off; off>>=1) sum += __shfl_xor(sum, off, 64);
  float inv = 1.0f / sum;
  #pragma unroll
  for (int j=0;j<8;j++) r[j] *= inv;
  if constexpr (WF32){
    *(float4*)(p + lane*4)       = make_float4(r[0],r[1],r[2],r[3]);
    *(float4*)(p + lane*4 + 256) = make_float4(r[4],r[5],r[6],r[7]);
  }
  if constexpr (SPLIT){
    unsigned long long ph=0, pl=0, qh=0, ql=0;
    #pragma unroll
    for (int j=0;j<4;j++){
      unsigned short h,l;
      fsplit(r[j],h,l);
      ph |= (unsigned long long)h << (16*j);  pl |= (unsigned long long)l << (16*j);
      fsplit(r[4+j],h,l);
      qh |= (unsigned long long)h << (16*j);  ql |= (unsigned long long)l << (16*j);
    }
    size_t base = (size_t)row * NC + lane*4;
    *(unsigned long long*)(sh + base)       = ph;
    *(unsigned long long*)(sl + base)       = pl;
    *(unsigned long long*)(sh + base + 256) = qh;
    *(unsigned long long*)(sl + base + 256) = ql;
  }
}

// ===== 128x256 8-wave split-bf16 GEMM, 2-deep counted-vmcnt pipeline (T4) =====
// C(m,n) = sum_k A[m][k]*B[n][k]   A: M x 512, B: N x 512 (both h+l planes)
// EPI 1: relu(acc+bias[n]) -> split OutH/OutL.
// EPI 2: Cf = (S2h+S2l) + scale[n]*acc
// 512 thr (8 waves, 64x64/wave), dbuf 2x48KB LDS (1 block/CU). Prologue stages
// tiles 0,1; iter t waits vmcnt(6) (tile t+1 loads stay in flight), raw
// barriers + explicit lgkmcnt(0)+sched_barrier (rule #18), stage tile t+2
// into the just-read buffer under the MFMAs. Same per-element MFMA order ->
// bit-identical. Block-level dead-tile skip (see R9).
template<int EPI>
__global__ void __launch_bounds__(512,1) gemmW_kernel(
    const unsigned short* __restrict__ Ah, const unsigned short* __restrict__ Al,
    const unsigned short* __restrict__ Bh, const unsigned short* __restrict__ Bl,
    unsigned short* __restrict__ OutH, unsigned short* __restrict__ OutL,
    float* __restrict__ Cf, const unsigned short* __restrict__ S2h,
    const unsigned short* __restrict__ S2l,
    const float* __restrict__ bias, const float* __restrict__ scale,
    const int* __restrict__ lenbuf, const int* __restrict__ cnumbuf,
    int K, long sA, long sB, long sC)
{
  __shared__ __align__(16) unsigned char smem[98304];  // 2 x (Ah8K Al8K Bh16K Bl16K)
  int flat = blockIdx.x;                      // grid = 1024, XCD-chunked remap
  int f2 = (flat & 7)*128 + (flat >> 3);
  int bx, by, bz;
  if constexpr (EPI==1){ bz = 0; bx = f2 >> 1; by = f2 & 1; }   // n fastest
  else { bz = f2 >> 5; int rem = f2 & 31; bx = rem >> 1; by = rem & 1; }
  Ah += (size_t)bz*sA; Al += (size_t)bz*sA;
  Bh += (size_t)bz*sB; Bl += (size_t)bz*sB;
  if constexpr (EPI==2){
    Cf += (size_t)bz*sC; S2h += (size_t)bz*sC; S2l += (size_t)bz*sC;
    scale += (size_t)bz*NC;
  }
  int m0 = bx*128, n0 = by*256;
  bool alive;
  if constexpr (EPI==1) alive = (m0 & 2047) < lenbuf[m0 >> 11];
  else                  alive = (m0 < lenbuf[bz]) && (n0 < cnumbuf[bz]);
  int tid = threadIdx.x;
  int l = tid & 63, wid = tid >> 6;
  int wr = wid >> 2, wc = wid & 3;     // wr: 64-row half (0..1), wc: 64-col strip (0..3)
  int lr = l & 15, lk = l >> 4;

  f32x4 acc[4][4] = {};

  if (alive){
    int offA[4], offB[4];
    #pragma unroll
    for (int i=0;i<4;i++){
      int ra = wr*64 + i*16 + lr;
      offA[i] = ra*64 + ((lk ^ ((ra>>1)&3))<<4);
      int rb = wc*64 + i*16 + lr;
      offB[i] = rb*64 + ((lk ^ ((rb>>1)&3))<<4);
    }

    // staging: A 128 rows x 64B = 8KB/plane (1 issue), B 256 rows = 16KB/plane
    // (2 issues); 6 gload16 per thread per K-tile.
    int srow = tid >> 2;                          // 0..127
    int gslot = (tid & 3) ^ ((srow>>1)&3);        // pre-swizzled global k-slot
    const unsigned short* gAh = Ah + (size_t)(m0 + srow)*512 + gslot*8;
    const unsigned short* gAl = Al + (size_t)(m0 + srow)*512 + gslot*8;
    const unsigned short* gBh = Bh + (size_t)(n0 + srow)*512 + gslot*8;
    const unsigned short* gBl = Bl + (size_t)(n0 + srow)*512 + gslot*8;
    const size_t RS2 = (size_t)128*512;

#define STAGEW(buf, k0) { \
    unsigned char* db = smem + (buf)*49152 + wid*1024; \
    gload16(gAh + (k0),       db); \
    gload16(gAl + (k0),       db + 8192); \
    gload16(gBh + (k0),       db + 16384); \
    gload16(gBh + (k0) + RS2, db + 24576); \
    gload16(gBl + (k0),       db + 32768); \
    gload16(gBl + (k0) + RS2, db + 40960); }

    int KT = K >> 5;          // 16
    STAGEW(0, 0)
    if (KT > 1) STAGEW(1, 32)
    for (int t = 0; t < KT; ++t){
      if (t < KT-1) asm volatile("s_waitcnt vmcnt(6)" ::: "memory");
      else          asm volatile("s_waitcnt vmcnt(0)" ::: "memory");
      __builtin_amdgcn_s_barrier();              // all waves' tile-t loads landed
      const unsigned char* base = smem + (t&1)*49152;
      short8v ah[4], al[4], bh[4], bl[4];
      #pragma unroll
      for (int i=0;i<4;i++){
        ah[i] = *(const short8v*)(base + offA[i]);
        al[i] = *(const short8v*)(base + 8192 + offA[i]);
        bh[i] = *(const short8v*)(base + 16384 + offB[i]);
        bl[i] = *(const short8v*)(base + 32768 + offB[i]);
      }
      asm volatile("s_waitcnt lgkmcnt(0)" ::: "memory");   // frags in regs
      __builtin_amdgcn_sched_barrier(0);
      __builtin_amdgcn_s_barrier();              // all waves done reading buf
      if (t+2 < KT) STAGEW(t&1, (t+2)*32)        // overwrite just-read buffer
      __builtin_amdgcn_s_setprio(1);
      #pragma unroll
      for (int i=0;i<4;i++)
        #pragma unroll
        for (int j=0;j<4;j++) acc[i][j] = MFMA16(ah[i], bh[j], acc[i][j]);
      #pragma unroll
      for (int i=0;i<4;i++)
        #pragma unroll
        for (int j=0;j<4;j++) acc[i][j] = MFMA16(ah[i], bl[j], acc[i][j]);
      #pragma unroll
      for (int i=0;i<4;i++)
        #pragma unroll
        for (int j=0;j<4;j++) acc[i][j] = MFMA16(al[i], bh[j], acc[i][j]);
      __builtin_amdgcn_s_setprio(0);
    }
#undef STAGEW
  }

  // epilogue
  float aux[4];
  #pragma unroll
  for (int j=0;j<4;j++){
    int gcol = n0 + wc*64 + j*16 + lr;
    if constexpr (EPI==1) aux[j] = bias[gcol];
    if constexpr (EPI==2) aux[j] = scale[gcol];
  }
  #pragma unroll
  for (int i=0;i<4;i++){
    #pragma unroll
    for (int r=0;r<4;r++){
      int grow = m0 + wr*64 + i*16 + lk*4 + r;
      size_t rowb = (size_t)grow*512 + n0 + wc*64 + lr;
      #pragma unroll
      for (int j=0;j<4;j++){
        float v = acc[i][j][r];
        if constexpr (EPI==1){
          v = fmaxf(v + aux[j], 0.f);
          unsigned short h,lo2; fsplit(v,h,lo2);
          OutH[rowb + j*16] = h; OutL[rowb + j*16] = lo2;
        } else {
          unsigned hh = S2h[rowb + j*16], ll = S2l[rowb + j*16];
          float s2 = __uint_as_float(hh<<16) + __uint_as_float(ll<<16);
          Cf[rowb + j*16] = s2 + aux[j]*v;
        }
      }
    }
  }
}

// ============ GEMM2: xn[c][h] = sum_n st[n][c] z[n][h], 128x128 tile ============
__global__ void __launch_bounds__(256,2) gemmT128_kernel(
    const unsigned short* __restrict__ Ah, const unsigned short* __restrict__ Al,
    const unsigned short* __restrict__ Bh, const unsigned short* __restrict__ Bl,
    unsigned short* __restrict__ OutH, unsigned short* __restrict__ OutL,
    float* __restrict__ parts, const int* __restrict__ lenbuf,
    const int* __restrict__ cnumbuf)
{
  __shared__ __align__(16) unsigned char smem[65536];  // 2 x (Ah8K Al8K Bh8K Bl8K)
  int flat = blockIdx.x;                    // grid = 512, XCD-chunked remap
  int f2 = (flat & 7)*64 + (flat >> 3);
  int bz = f2 >> 4; int rem = f2 & 15; int bx = rem >> 2; int by = rem & 3;
  size_t boff = (size_t)bz * NN * 512;
  Ah += boff; Al += boff; Bh += boff; Bl += boff;
  int m0 = bx*128, n0 = by*128;             // m0: c-block, n0: h-block
  int KT = (lenbuf[bz] + 31) >> 5;
  int limc = cnumbuf[bz] - m0;
  bool alive = (limc > 0);
  int tid = threadIdx.x;
  int l = tid & 63, wid = tid >> 6;
  int wr = wid >> 1, wc = wid & 1;
  int lr = l & 15, lk = l >> 4;

  f32x4 acc[4][4] = {};

  if (alive){
    bool liA[4];
    int offA[4], offB[4];
    #pragma unroll
    for (int i=0;i<4;i++){
      int ra = wr*64 + i*16 + lr;
      offA[i] = ra*64 + ((lk ^ ((ra>>1)&3) ^ ((ra>>3)&3))<<4);
      liA[i] = (wr*64 + i*16) < limc;
      int rb = wc*64 + i*16 + lr;
      offB[i] = rb*64 + ((lk ^ ((rb>>1)&3) ^ ((rb>>3)&3))<<4);
    }

    int np  = tid & 15;          // n-pair: rows 2np, 2np+1 of the k-tile
    int seg = tid >> 4;          // 0..15 : 8-col segment

    short8v ra0h, ra1h, ra0l, ra1l, rb0h, rb1h, rb0l, rb1l;

#define TLOAD(k0) { \
    size_t ga = (size_t)((k0) + 2*np)*512 + m0 + seg*8; \
    ra0h = *(const short8v*)(Ah + ga); ra1h = *(const short8v*)(Ah + ga + 512); \
    ra0l = *(const short8v*)(Al + ga); ra1l = *(const short8v*)(Al + ga + 512); \
    size_t gb = (size_t)((k0) + 2*np)*512 + n0 + seg*8; \
    rb0h = *(const short8v*)(Bh + gb); rb1h = *(const short8v*)(Bh + gb + 512); \
    rb0l = *(const short8v*)(Bl + gb); rb1l = *(const short8v*)(Bl + gb + 512); }

#define TWRITE(buf) { \
    unsigned char* bb = smem + (buf)*32768; \
    _Pragma("unroll") \
    for (int k=0;k<8;k++){ \
      int c = seg*8 + k; \
      int ps = (np>>2) ^ ((c>>1)&3) ^ ((c>>3)&3); \
      int byo = c*64 + ps*16 + (np&3)*4; \
      *(unsigned int*)(bb + byo)         = (unsigned int)(unsigned short)ra0h[k] | ((unsigned int)(unsigned short)ra1h[k]<<16); \
      *(unsigned int*)(bb + 8192 + byo)  = (unsigned int)(unsigned short)ra0l[k] | ((unsigned int)(unsigned short)ra1l[k]<<16); \
      *(unsigned int*)(bb + 16384 + byo) = (unsigned int)(unsigned short)rb0h[k] | ((unsigned int)(unsigned short)rb1h[k]<<16); \
      *(unsigned int*)(bb + 24576 + byo) = (unsigned int)(unsigned short)rb0l[k] | ((unsigned int)(unsigned short)rb1l[k]<<16); } }

    TLOAD(0)
    TWRITE(0)
    __syncthreads();
    for (int t = 0; t < KT; ++t){
      int more = (t+1 < KT);
      if (more) TLOAD((t+1)*32)
      const unsigned char* base = smem + (t&1)*32768;
      short8v ah[4], bh[4], bl[4];
      #pragma unroll
      for (int i=0;i<4;i++) if (liA[i]) ah[i] = *(const short8v*)(base + offA[i]);
      #pragma unroll
      for (int j=0;j<4;j++){
        bh[j] = *(const short8v*)(base + 16384 + offB[j]);
        bl[j] = *(const short8v*)(base + 24576 + offB[j]);
      }
      __builtin_amdgcn_s_setprio(1);
      #pragma unroll
      for (int i=0;i<4;i++) if (liA[i])
        #pragma unroll
        for (int j=0;j<4;j++) acc[i][j] = MFMA16(ah[i], bh[j], acc[i][j]);
      #pragma unroll
      for (int i=0;i<4;i++) if (liA[i])
        #pragma unroll
        for (int j=0;j<4;j++) acc[i][j] = MFMA16(ah[i], bl[j], acc[i][j]);
      #pragma unroll
      for (int i=0;i<4;i++) if (liA[i]){
        short8v al = *(const short8v*)(base + 8192 + offA[i]);
        #pragma unroll
        for (int j=0;j<4;j++) acc[i][j] = MFMA16(al, bh[j], acc[i][j]);
      }
      __builtin_amdgcn_s_setprio(0);
      if (more) TWRITE((t+1)&1)
      __syncthreads();
    }
#undef TLOAD
#undef TWRITE
  }

  // epilogue: split store + per-c-row sum-of-squares partials
  #pragma unroll
  for (int i=0;i<4;i++){
    #pragma unroll
    for (int r=0;r<4;r++){
      int grow = m0 + wr*64 + i*16 + lk*4 + r;     // c index
      float p = 0.f;
      size_t rowb = (size_t)bz*NC*NH + (size_t)grow*512 + n0 + wc*64 + lr;
      #pragma unroll
      for (int j=0;j<4;j++){
        float v = acc[i][j][r];
        p = fmaf(v,v,p);
        unsigned short h,lo2; fsplit(v,h,lo2);
        OutH[rowb + j*16] = h; OutL[rowb + j*16] = lo2;
      }
      p += __shfl_xor(p, 1, 64);
      p += __shfl_xor(p, 2, 64);
      p += __shfl_xor(p, 4, 64);
      p += __shfl_xor(p, 8, 64);
      if (lr == 0) parts[(((size_t)bz*NC) + grow)*8 + by*2 + wc] = p;
    }
  }
}

// ---------------- squash scale from partials ----------------
__global__ void __launch_bounds__(512) scale_kernel(const float* __restrict__ parts,
                                                    float* __restrict__ scale){
  int b = blockIdx.x, c = threadIdx.x;
  const float* p = parts + ((size_t)b*NC + c)*8;
  float m2 = ((p[0]+p[1])+(p[2]+p[3])) + ((p[4]+p[5])+(p[6]+p[7]));
  float sc = 0.0f;
  if (m2 > 0.0f) sc = (m2/(1.0f+m2)) / sqrtf(m2);
  scale[(size_t)b*NC + c] = sc;
}

// ---------------- orchestration ----------------
extern "C" void kernel_launch(void* const* d_in, const int* in_sizes, int n_in,
                              void* d_out, int out_size, void* d_ws, size_t ws_size,
                              hipStream_t stream) {
  const float* x    = (const float*)d_in[0];
  const float* adj  = (const float*)d_in[1];
  const float* W    = (const float*)d_in[2];
  const float* bias = (const float*)d_in[3];
  const unsigned char* mask = (const unsigned char*)d_in[4];
  float* out = (float*)d_out;                 // holds s (f32) and finally softmax(s)
  char* ws = (char*)d_ws;

  unsigned short* zh   = (unsigned short*)(ws);                 // 64 MB
  unsigned short* zl   = (unsigned short*)(ws + 67108864);      // 64 MB
  unsigned short* sth  = (unsigned short*)(ws + 134217728);     // 64 MB (aliases yh)
  unsigned short* stl  = (unsigned short*)(ws + 201326592);     // 64 MB (aliases yl)
  unsigned short* xnh  = (unsigned short*)(ws + 268435456);     // 16 MB
  unsigned short* xnl  = (unsigned short*)(ws + 285212672);     // 16 MB
  unsigned short* WTh  = (unsigned short*)(ws + 301989888);     // 0.5 MB
  unsigned short* WTl  = (unsigned short*)(ws + 302514176);     // 0.5 MB
  float* parts         = (float*)(ws + 303038464);              // 0.5 MB
  float* scalebuf      = (float*)(ws + 304087040);              // 64 KB
  int*   cnum          = (int*)(ws + 304152576);                // 128 B
  int*   lenbuf        = (int*)(ws + 304152704);                // 128 B
  unsigned short* yh = sth;
  unsigned short* yl = stl;

  counts_kernel<<<NB, 256, 0, stream>>>(mask, cnum, lenbuf);
  wsplit_kernel<<<dim3(16,16), 256, 0, stream>>>(W, WTh, WTl);
  spmm_kernel<<<ROWS, 256, 0, stream>>>(adj, x, yh, yl, lenbuf);
  // z = relu(y @ W + b): M=65536 N=512 K=512; 128x256 tiles, pipelined
  gemmW_kernel<1><<<1024, 512, 0, stream>>>(
      yh, yl, WTh, WTl, zh, zl, nullptr, nullptr, nullptr, bias, nullptr,
      lenbuf, cnum, ND, 0, 0, 0);

  for (int it = 0; it < 3; ++it){
    // s~ = masked_softmax(s): iteration 0 fuses the threefry RNG
    if (it == 0)
      rngsm_kernel<<<ROWS/4, 256, 0, stream>>>(sth, stl, cnum);
    else
      softmax_kernel<true,false><<<ROWS/4, 256, 0, stream>>>(out, sth, stl, cnum);
    // xn[c][h] = sum_n s~[n][c] z[n][h]  (+ c-row sumsq partials)
    gemmT128_kernel<<<512, 256, 0, stream>>>(
        sth, stl, zh, zl, xnh, xnl, parts, lenbuf, cnum);
    scale_kernel<<<NB, 512, 0, stream>>>(parts, scalebuf);
    // s = (sth+stl) + scale[c] * (z @ xn^T): M=2048 N=512 K=512 per batch
    gemmW_kernel<2><<<1024, 512, 0, stream>>>(
        zh, zl, xnh, xnl, nullptr, nullptr, out, sth, stl, nullptr, scalebuf,
        lenbuf, cnum, NH, (long)NN*NH, (long)NC*NH, (long)NN*NC);
  }
  softmax_kernel<false,true><<<ROWS/4, 256, 0, stream>>>(out, nullptr, nullptr, cnum);
}

// Round 17
// 1291.754 us; speedup vs baseline: 1.0540x; 1.0540x over previous
//
#include <hip/hip_runtime.h>
#include <cstdint>
#include <cstddef>

#define NB 32
#define NN 2048
#define ND 512
#define NH 512
#define NC 512
#define ROWS (NB*NN)                 // 65536

typedef __attribute__((ext_vector_type(8))) short short8v;   // 8 bf16 (4 VGPR)
typedef __attribute__((ext_vector_type(4))) float f32x4;

#define MFMA16(a,b,c) __builtin_amdgcn_mfma_f32_16x16x32_bf16((a),(b),(c),0,0,0)

typedef const __attribute__((address_space(1))) unsigned int* gas_t;
typedef __attribute__((address_space(3))) unsigned int* las_t;

__device__ __forceinline__ void gload16(const void* g, void* l){
  __builtin_amdgcn_global_load_lds((gas_t)g, (las_t)l, 16, 0, 0);
}

// f32 -> bf16 hi/lo split (RNE both).  v ~= h + l, |v-h-l| <= 2^-18 |v|
__device__ __forceinline__ void fsplit(float v, unsigned short& h, unsigned short& l){
  unsigned u = __float_as_uint(v);
  unsigned hb = (u + 0x7FFFu + ((u>>16)&1u)) >> 16;
  float hf = __uint_as_float(hb<<16);
  float r = v - hf;
  unsigned ur = __float_as_uint(r);
  l = (unsigned short)((ur + 0x7FFFu + ((ur>>16)&1u)) >> 16);
  h = (unsigned short)hb;
}

// ---------------- threefry2x32-20 (JAX partitionable scheme) ----------------
__device__ __forceinline__ unsigned rotl32(unsigned x, int d){ return (x<<d)|(x>>(32-d)); }

__device__ __forceinline__ unsigned threefry_xor(unsigned k0, unsigned k1, unsigned c0, unsigned c1){
  unsigned ks2 = 0x1BD11BDAu ^ k0 ^ k1;
  unsigned x0 = c0 + k0, x1 = c1 + k1;
#define TF_RND(r) { x0 += x1; x1 = rotl32(x1,(r)); x1 ^= x0; }
  TF_RND(13) TF_RND(15) TF_RND(26) TF_RND(6)
  x0 += k1;  x1 += ks2 + 1u;
  TF_RND(17) TF_RND(29) TF_RND(16) TF_RND(24)
  x0 += ks2; x1 += k0 + 2u;
  TF_RND(13) TF_RND(15) TF_RND(26) TF_RND(6)
  x0 += k0;  x1 += k1 + 3u;
  TF_RND(17) TF_RND(29) TF_RND(16) TF_RND(24)
  x0 += k1;  x1 += ks2 + 4u;
  TF_RND(13) TF_RND(15) TF_RND(26) TF_RND(6)
  x0 += ks2; x1 += k0 + 5u;
#undef TF_RND
  return x0 ^ x1;
}

__device__ __forceinline__ float bits_to_normal(unsigned bits){
  float f = __uint_as_float((bits >> 9) | 0x3f800000u) - 1.0f;
  const float lo = -0.99999994f;
  float u = fmaxf(lo, fmaf(f, 2.0f, lo));
  float w = -log1pf(-(u*u));
  float p;
  if (w < 5.0f){
    w -= 2.5f;
    p =            2.81022636e-08f;
    p = fmaf(p, w, 3.43273939e-07f);
    p = fmaf(p, w, -3.5233877e-06f);
    p = fmaf(p, w, -4.39150654e-06f);
    p = fmaf(p, w, 0.00021858087f);
    p = fmaf(p, w, -0.00125372503f);
    p = fmaf(p, w, -0.00417768164f);
    p = fmaf(p, w, 0.246640727f);
    p = fmaf(p, w, 1.50140941f);
  } else {
    w = sqrtf(w) - 3.0f;
    p =            -0.000200214257f;
    p = fmaf(p, w, 0.000100950558f);
    p = fmaf(p, w, 0.00134934322f);
    p = fmaf(p, w, -0.00367342844f);
    p = fmaf(p, w, 0.00573950773f);
    p = fmaf(p, w, -0.0076224613f);
    p = fmaf(p, w, 0.00943887047f);
    p = fmaf(p, w, 1.00167406f);
    p = fmaf(p, w, 2.83297682f);
  }
  return 1.4142135623730951f * (p * u);
}

// ---------------- cluster counts + lens ----------------
__global__ void __launch_bounds__(256) counts_kernel(const unsigned char* __restrict__ mraw,
                                                     int* __restrict__ cnum,
                                                     int* __restrict__ lenbuf){
  __shared__ int red[256];
  int b = blockIdx.x, tid = threadIdx.x;
  unsigned char b0 = mraw[0], b1 = mraw[1];
  int cnt = 0;
  if (b0 == 1 && b1 == 1){
    const unsigned char* p = mraw + (size_t)b * NN;
    for (int i = tid; i < NN; i += 256) cnt += (p[i] != 0);
  } else if (b0 == 1){
    const int* p = (const int*)mraw + (size_t)b * NN;
    for (int i = tid; i < NN; i += 256) cnt += (p[i] != 0);
  } else {
    const float* p = (const float*)mraw + (size_t)b * NN;
    for (int i = tid; i < NN; i += 256) cnt += (p[i] != 0.0f);
  }
  red[tid] = cnt; __syncthreads();
  for (int off = 128; off; off >>= 1){ if (tid < off) red[tid] += red[tid+off]; __syncthreads(); }
  if (tid == 0){ cnum[b] = red[0] >> 2; lenbuf[b] = red[0]; }
}

// ---------------- y = adj @ x (adj in {0,1}), wave-scan compaction ----------------
__global__ void __launch_bounds__(256) spmm_kernel(const float* __restrict__ adj,
                                                   const float* __restrict__ x,
                                                   unsigned short* __restrict__ yh,
                                                   unsigned short* __restrict__ yl,
                                                   const int* __restrict__ lenbuf){
  __shared__ int idxs[NN];
  __shared__ int wtot[4];
  int row = blockIdx.x;
  int b = row >> 11;
  int n = row & 2047;
  int tid = threadIdx.x;
  int l = tid & 63, w = tid >> 6;
  size_t base = (size_t)row * ND;
  if (n >= lenbuf[b]){      // adj row all-zero: y = 0 (skip 8KB adj read)
    yh[base+tid]=0; yl[base+tid]=0; yh[base+tid+256]=0; yl[base+tid+256]=0;
    return;
  }
  const float* arow = adj + (size_t)row * NN;
  float v[8];
  *(float4*)&v[0] = *(const float4*)(arow + tid*8);
  *(float4*)&v[4] = *(const float4*)(arow + tid*8 + 4);
  int lc = 0;
  #pragma unroll
  for (int j=0;j<8;j++) lc += (v[j] != 0.0f);
  // wave-level inclusive scan (no barriers), then 1-barrier cross-wave combine
  int sc = lc;
  #pragma unroll
  for (int off=1; off<64; off<<=1){
    int t = __shfl_up(sc, off, 64);
    if (l >= off) sc += t;
  }
  if (l == 63) wtot[w] = sc;
  __syncthreads();
  int basep = 0;
  #pragma unroll
  for (int i=0;i<4;i++) if (i < w) basep += wtot[i];
  int total = wtot[0]+wtot[1]+wtot[2]+wtot[3];
  int pos = basep + sc - lc;
  #pragma unroll
  for (int j=0;j<8;j++){
    if (v[j] != 0.0f){ idxs[pos++] = tid*8 + j; }
  }
  __syncthreads();
  float acc0 = 0.f, acc1 = 0.f;
  const float* xb = x + (size_t)b * NN * ND;
  int j = 0;
  for (; j+4 <= total; j += 4){
    int m0_=idxs[j], m1_=idxs[j+1], m2_=idxs[j+2], m3_=idxs[j+3];
    float a0 = xb[(size_t)m0_*ND + tid], a1 = xb[(size_t)m1_*ND + tid];
    float a2 = xb[(size_t)m2_*ND + tid], a3 = xb[(size_t)m3_*ND + tid];
    float b0 = xb[(size_t)m0_*ND + tid + 256], b1 = xb[(size_t)m1_*ND + tid + 256];
    float b2 = xb[(size_t)m2_*ND + tid + 256], b3 = xb[(size_t)m3_*ND + tid + 256];
    acc0 += a0; acc0 += a1; acc0 += a2; acc0 += a3;
    acc1 += b0; acc1 += b1; acc1 += b2; acc1 += b3;
  }
  for (; j < total; j++){
    int m_ = idxs[j];
    acc0 += xb[(size_t)m_*ND + tid];
    acc1 += xb[(size_t)m_*ND + tid + 256];
  }
  unsigned short h,lo;
  fsplit(acc0,h,lo); yh[base+tid]=h;     yl[base+tid]=lo;
  fsplit(acc1,h,lo); yh[base+tid+256]=h; yl[base+tid+256]=lo;
}

// ---------------- W transpose + split: WT[h][d] ----------------
__global__ void __launch_bounds__(256) wsplit_kernel(const float* __restrict__ W,
                                                     unsigned short* __restrict__ WTh,
                                                     unsigned short* __restrict__ WTl){
  __shared__ float t[32][33];
  int bx = blockIdx.x, by = blockIdx.y;
  int x = threadIdx.x & 31, y = threadIdx.x >> 5;
  for (int yy=y; yy<32; yy+=8) t[yy][x] = W[(size_t)(bx*32+yy)*512 + by*32 + x];
  __syncthreads();
  for (int yy=y; yy<32; yy+=8){
    float v = t[x][yy];                     // = W[bx*32+x][by*32+yy]
    unsigned short h,l; fsplit(v,h,l);
    size_t idx = (size_t)(by*32+yy)*512 + bx*32 + x;
    WTh[idx]=h; WTl[idx]=l;
  }
}

// ---------------- fused rng + masked softmax #1 (split planes only) ----------
// Values identical to rng_kernel (counter = row*512 + c) and reduce/split
// identical to softmax_kernel<true,false> -> bit-identical pipeline.
__global__ void __launch_bounds__(256) rngsm_kernel(unsigned short* __restrict__ sh,
                                                    unsigned short* __restrict__ sl,
                                                    const int* __restrict__ cnum){
  int row  = blockIdx.x*4 + (threadIdx.x >> 6);
  int lane = threadIdx.x & 63;
  int Kc = cnum[row >> 11];
  float e[8];
  #pragma unroll
  for (int j=0;j<8;j++){
    int c = (j<4) ? lane*4 + j : lane*4 + 252 + j;
    e[j] = bits_to_normal(threefry_xor(0u, 42u, 0u, (unsigned)row*512u + (unsigned)c));
  }
  float m = -3.0e38f;
  #pragma unroll
  for (int j=0;j<8;j++){
    int c = (j<4) ? lane*4 + j : lane*4 + 252 + j;
    if (c < Kc) m = fmaxf(m, e[j]);
  }
  #pragma unroll
  for (int off=32; off; off>>=1) m = fmaxf(m, __shfl_xor(m, off, 64));
  float r[8]; float sum = 0.f;
  #pragma unroll
  for (int j=0;j<8;j++){
    int c = (j<4) ? lane*4 + j : lane*4 + 252 + j;
    r[j] = (c < Kc) ? expf(e[j] - m) : 0.0f;
    sum += r[j];
  }
  #pragma unroll
  for (int off=32; off; off>>=1) sum += __shfl_xor(sum, off, 64);
  float inv = 1.0f / sum;
  #pragma unroll
  for (int j=0;j<8;j++) r[j] *= inv;
  unsigned long long ph=0, pl=0, qh=0, ql=0;
  #pragma unroll
  for (int j=0;j<4;j++){
    unsigned short h,l;
    fsplit(r[j],h,l);
    ph |= (unsigned long long)h << (16*j);  pl |= (unsigned long long)l << (16*j);
    fsplit(r[4+j],h,l);
    qh |= (unsigned long long)h << (16*j);  ql |= (unsigned long long)l << (16*j);
  }
  size_t base = (size_t)row * NC + lane*4;
  *(unsigned long long*)(sh + base)       = ph;
  *(unsigned long long*)(sl + base)       = pl;
  *(unsigned long long*)(sh + base + 256) = qh;
  *(unsigned long long*)(sl + base + 256) = ql;
}

// ---------------- masked softmax ----------------
// SPLIT: write bf16 h/l planes.  WF32: write f32 result in-place.
template<bool SPLIT, bool WF32>
__global__ void __launch_bounds__(256) softmax_kernel(float* __restrict__ s,
                                                      unsigned short* __restrict__ sh,
                                                      unsigned short* __restrict__ sl,
                                                      const int* __restrict__ cnum){
  int row  = blockIdx.x*4 + (threadIdx.x >> 6);
  int lane = threadIdx.x & 63;
  int b = row >> 11;
  int Kc = cnum[b];
  float* p = s + (size_t)row * NC;
  float4 v0 = *(const float4*)(p + lane*4);
  float4 v1 = *(const float4*)(p + lane*4 + 256);
  float e[8] = {v0.x,v0.y,v0.z,v0.w,v1.x,v1.y,v1.z,v1.w};
  float m = -3.0e38f;
  #pragma unroll
  for (int j=0;j<8;j++){
    int c = (j<4) ? lane*4 + j : lane*4 + 252 + j;
    if (c < Kc) m = fmaxf(m, e[j]);
  }
  #pragma unroll
  for (int off=32; off; off>>=1) m = fmaxf(m, __shfl_xor(m, off, 64));
  float r[8]; float sum = 0.f;
  #pragma unroll
  for (int j=0;j<8;j++){
    int c = (j<4) ? lane*4 + j : lane*4 + 252 + j;
    r[j] = (c < Kc) ? expf(e[j] - m) : 0.0f;
    sum += r[j];
  }
  #pragma unroll
  for (int off=32; off; off>>=1) sum += __shfl_xor(sum, off, 64);
  float inv = 1.0f / sum;
  #pragma unroll
  for (int j=0;j<8;j++) r[j] *= inv;
  if constexpr (WF32){
    *(float4*)(p + lane*4)       = make_float4(r[0],r[1],r[2],r[3]);
    *(float4*)(p + lane*4 + 256) = make_float4(r[4],r[5],r[6],r[7]);
  }
  if constexpr (SPLIT){
    unsigned long long ph=0, pl=0, qh=0, ql=0;
    #pragma unroll
    for (int j=0;j<4;j++){
      unsigned short h,l;
      fsplit(r[j],h,l);
      ph |= (unsigned long long)h << (16*j);  pl |= (unsigned long long)l << (16*j);
      fsplit(r[4+j],h,l);
      qh |= (unsigned long long)h << (16*j);  ql |= (unsigned long long)l << (16*j);
    }
    size_t base = (size_t)row * NC + lane*4;
    *(unsigned long long*)(sh + base)       = ph;
    *(unsigned long long*)(sl + base)       = pl;
    *(unsigned long long*)(sh + base + 256) = qh;
    *(unsigned long long*)(sl + base + 256) = ql;
  }
}

// ============ 128x256 4-wave split-bf16 GEMM (wide N halves A-panel dup) ======
// C(m,n) = sum_k A[m][k]*B[n][k]   A: M x 512, B: N x 512 (both h+l planes)
// EPI 1: relu(acc+bias[n]) -> split OutH/OutL.
// EPI 2: Cf = (S2h+S2l) + scale[n]*acc   (S2 reconstructed from bf16 planes)
// 256 thr, single 48KB LDS buffer -> 2 blocks/CU; frag front-load (R6 pattern).
// Block-level dead-tile skip (bit-identical; see R9).
template<int EPI>
__global__ void __launch_bounds__(256,2) gemmW_kernel(
    const unsigned short* __restrict__ Ah, const unsigned short* __restrict__ Al,
    const unsigned short* __restrict__ Bh, const unsigned short* __restrict__ Bl,
    unsigned short* __restrict__ OutH, unsigned short* __restrict__ OutL,
    float* __restrict__ Cf, const unsigned short* __restrict__ S2h,
    const unsigned short* __restrict__ S2l,
    const float* __restrict__ bias, const float* __restrict__ scale,
    const int* __restrict__ lenbuf, const int* __restrict__ cnumbuf,
    int K, long sA, long sB, long sC)
{
  __shared__ __align__(16) unsigned char smem[49152];  // A:0..16K (h,l) B:16..48K
  int flat = blockIdx.x;                      // grid = 1024, XCD-chunked remap
  int f2 = (flat & 7)*128 + (flat >> 3);
  int bx, by, bz;
  if constexpr (EPI==1){ bz = 0; bx = f2 >> 1; by = f2 & 1; }   // n fastest
  else { bz = f2 >> 5; int rem = f2 & 31; bx = rem >> 1; by = rem & 1; }
  Ah += (size_t)bz*sA; Al += (size_t)bz*sA;
  Bh += (size_t)bz*sB; Bl += (size_t)bz*sB;
  if constexpr (EPI==2){
    Cf += (size_t)bz*sC; S2h += (size_t)bz*sC; S2l += (size_t)bz*sC;
    scale += (size_t)bz*NC;
  }
  int m0 = bx*128, n0 = by*256;
  bool alive;
  if constexpr (EPI==1) alive = (m0 & 2047) < lenbuf[m0 >> 11];
  else                  alive = (m0 < lenbuf[bz]) && (n0 < cnumbuf[bz]);
  int tid = threadIdx.x;
  int l = tid & 63, wid = tid >> 6;
  int wr = wid >> 1, wc = wid & 1;           // wr: 64-row half, wc: 128-col half
  int lr = l & 15, lk = l >> 4;

  f32x4 acc[4][8] = {};

  if (alive){
    int offA[4], offB[8];
    #pragma unroll
    for (int i=0;i<4;i++){
      int ra = wr*64 + i*16 + lr;
      offA[i] = ra*64 + ((lk ^ ((ra>>1)&3))<<4);
    }
    #pragma unroll
    for (int j=0;j<8;j++){
      int rb = wc*128 + j*16 + lr;
      offB[j] = rb*64 + ((lk ^ ((rb>>1)&3))<<4);
    }

    // staging: A 128 rows (2x4KB/plane), B 256 rows (4x4KB/plane); 12 issues
    int srow = tid >> 2;                          // 0..63
    int gslot = (tid & 3) ^ ((srow>>1)&3);        // pre-swizzled global k-slot
    const unsigned short* gAh = Ah + (size_t)(m0 + srow)*512 + gslot*8;
    const unsigned short* gAl = Al + (size_t)(m0 + srow)*512 + gslot*8;
    const unsigned short* gBh = Bh + (size_t)(n0 + srow)*512 + gslot*8;
    const unsigned short* gBl = Bl + (size_t)(n0 + srow)*512 + gslot*8;
    const size_t RS = (size_t)64*512;

#define STAGEW(k0) { \
    unsigned char* db = smem + wid*1024; \
    gload16(gAh + (k0),        db);           gload16(gAh + (k0) + RS,   db + 4096); \
    gload16(gAl + (k0),        db + 8192);    gload16(gAl + (k0) + RS,   db + 12288); \
    gload16(gBh + (k0),        db + 16384);   gload16(gBh + (k0) + RS,   db + 20480); \
    gload16(gBh + (k0) + 2*RS, db + 24576);   gload16(gBh + (k0) + 3*RS, db + 28672); \
    gload16(gBl + (k0),        db + 32768);   gload16(gBl + (k0) + RS,   db + 36864); \
    gload16(gBl + (k0) + 2*RS, db + 40960);   gload16(gBl + (k0) + 3*RS, db + 45056); }

    STAGEW(0)
    int KT = K >> 5;
    for (int t = 0; t < KT; ++t){
      asm volatile("s_waitcnt vmcnt(0)" ::: "memory");   // stage of tile t done
      __syncthreads();
      short8v ah[4], al[4], bh[8], bl[8];
      #pragma unroll
      for (int i=0;i<4;i++){
        ah[i] = *(const short8v*)(smem + offA[i]);
        al[i] = *(const short8v*)(smem + 8192 + offA[i]);
      }
      #pragma unroll
      for (int j=0;j<8;j++){
        bh[j] = *(const short8v*)(smem + 16384 + offB[j]);
        bl[j] = *(const short8v*)(smem + 32768 + offB[j]);
      }
      __syncthreads();                 // all waves read -> safe to overwrite
      if (t+1 < KT) STAGEW((t+1)*32)   // async loads fly under the MFMA phase
      __builtin_amdgcn_s_setprio(1);
      #pragma unroll
      for (int i=0;i<4;i++)
        #pragma unroll
        for (int j=0;j<8;j++) acc[i][j] = MFMA16(ah[i], bh[j], acc[i][j]);
      #pragma unroll
      for (int i=0;i<4;i++)
        #pragma unroll
        for (int j=0;j<8;j++) acc[i][j] = MFMA16(ah[i], bl[j], acc[i][j]);
      #pragma unroll
      for (int i=0;i<4;i++)
        #pragma unroll
        for (int j=0;j<8;j++) acc[i][j] = MFMA16(al[i], bh[j], acc[i][j]);
      __builtin_amdgcn_s_setprio(0);
    }
#undef STAGEW
  }

  // epilogue
  float aux[8];
  #pragma unroll
  for (int j=0;j<8;j++){
    int gcol = n0 + wc*128 + j*16 + lr;
    if constexpr (EPI==1) aux[j] = bias[gcol];
    if constexpr (EPI==2) aux[j] = scale[gcol];
  }
  #pragma unroll
  for (int i=0;i<4;i++){
    #pragma unroll
    for (int r=0;r<4;r++){
      int grow = m0 + wr*64 + i*16 + lk*4 + r;
      size_t rowb = (size_t)grow*512 + n0 + wc*128 + lr;
      #pragma unroll
      for (int j=0;j<8;j++){
        float v = acc[i][j][r];
        if constexpr (EPI==1){
          v = fmaxf(v + aux[j], 0.f);
          unsigned short h,lo2; fsplit(v,h,lo2);
          OutH[rowb + j*16] = h; OutL[rowb + j*16] = lo2;
        } else {
          unsigned hh = S2h[rowb + j*16], ll = S2l[rowb + j*16];
          float s2 = __uint_as_float(hh<<16) + __uint_as_float(ll<<16);
          Cf[rowb + j*16] = s2 + aux[j]*v;
        }
      }
    }
  }
}

// ============ GEMM2: xn[c][h] = sum_n st[n][c] z[n][h], 128x128 tile ============
__global__ void __launch_bounds__(256,2) gemmT128_kernel(
    const unsigned short* __restrict__ Ah, const unsigned short* __restrict__ Al,
    const unsigned short* __restrict__ Bh, const unsigned short* __restrict__ Bl,
    unsigned short* __restrict__ OutH, unsigned short* __restrict__ OutL,
    float* __restrict__ parts, const int* __restrict__ lenbuf,
    const int* __restrict__ cnumbuf)
{
  __shared__ __align__(16) unsigned char smem[65536];  // 2 x (Ah8K Al8K Bh8K Bl8K)
  int flat = blockIdx.x;                    // grid = 512, XCD-chunked remap
  int f2 = (flat & 7)*64 + (flat >> 3);
  int bz = f2 >> 4; int rem = f2 & 15; int bx = rem >> 2; int by = rem & 3;
  size_t boff = (size_t)bz * NN * 512;
  Ah += boff; Al += boff; Bh += boff; Bl += boff;
  int m0 = bx*128, n0 = by*128;             // m0: c-block, n0: h-block
  int KT = (lenbuf[bz] + 31) >> 5;
  int limc = cnumbuf[bz] - m0;
  bool alive = (limc > 0);
  int tid = threadIdx.x;
  int l = tid & 63, wid = tid >> 6;
  int wr = wid >> 1, wc = wid & 1;
  int lr = l & 15, lk = l >> 4;

  f32x4 acc[4][4] = {};

  if (alive){
    bool liA[4];
    int offA[4], offB[4];
    #pragma unroll
    for (int i=0;i<4;i++){
      int ra = wr*64 + i*16 + lr;
      offA[i] = ra*64 + ((lk ^ ((ra>>1)&3) ^ ((ra>>3)&3))<<4);
      liA[i] = (wr*64 + i*16) < limc;
      int rb = wc*64 + i*16 + lr;
      offB[i] = rb*64 + ((lk ^ ((rb>>1)&3) ^ ((rb>>3)&3))<<4);
    }

    int np  = tid & 15;          // n-pair: rows 2np, 2np+1 of the k-tile
    int seg = tid >> 4;          // 0..15 : 8-col segment

    short8v ra0h, ra1h, ra0l, ra1l, rb0h, rb1h, rb0l, rb1l;

#define TLOAD(k0) { \
    size_t ga = (size_t)((k0) + 2*np)*512 + m0 + seg*8; \
    ra0h = *(const short8v*)(Ah + ga); ra1h = *(const short8v*)(Ah + ga + 512); \
    ra0l = *(const short8v*)(Al + ga); ra1l = *(const short8v*)(Al + ga + 512); \
    size_t gb = (size_t)((k0) + 2*np)*512 + n0 + seg*8; \
    rb0h = *(const short8v*)(Bh + gb); rb1h = *(const short8v*)(Bh + gb + 512); \
    rb0l = *(const short8v*)(Bl + gb); rb1l = *(const short8v*)(Bl + gb + 512); }

#define TWRITE(buf) { \
    unsigned char* bb = smem + (buf)*32768; \
    _Pragma("unroll") \
    for (int k=0;k<8;k++){ \
      int c = seg*8 + k; \
      int ps = (np>>2) ^ ((c>>1)&3) ^ ((c>>3)&3); \
      int byo = c*64 + ps*16 + (np&3)*4; \
      *(unsigned int*)(bb + byo)         = (unsigned int)(unsigned short)ra0h[k] | ((unsigned int)(unsigned short)ra1h[k]<<16); \
      *(unsigned int*)(bb + 8192 + byo)  = (unsigned int)(unsigned short)ra0l[k] | ((unsigned int)(unsigned short)ra1l[k]<<16); \
      *(unsigned int*)(bb + 16384 + byo) = (unsigned int)(unsigned short)rb0h[k] | ((unsigned int)(unsigned short)rb1h[k]<<16); \
      *(unsigned int*)(bb + 24576 + byo) = (unsigned int)(unsigned short)rb0l[k] | ((unsigned int)(unsigned short)rb1l[k]<<16); } }

    TLOAD(0)
    TWRITE(0)
    __syncthreads();
    for (int t = 0; t < KT; ++t){
      int more = (t+1 < KT);
      if (more) TLOAD((t+1)*32)
      const unsigned char* base = smem + (t&1)*32768;
      short8v ah[4], bh[4], bl[4];
      #pragma unroll
      for (int i=0;i<4;i++) if (liA[i]) ah[i] = *(const short8v*)(base + offA[i]);
      #pragma unroll
      for (int j=0;j<4;j++){
        bh[j] = *(const short8v*)(base + 16384 + offB[j]);
        bl[j] = *(const short8v*)(base + 24576 + offB[j]);
      }
      __builtin_amdgcn_s_setprio(1);
      #pragma unroll
      for (int i=0;i<4;i++) if (liA[i])
        #pragma unroll
        for (int j=0;j<4;j++) acc[i][j] = MFMA16(ah[i], bh[j], acc[i][j]);
      #pragma unroll
      for (int i=0;i<4;i++) if (liA[i])
        #pragma unroll
        for (int j=0;j<4;j++) acc[i][j] = MFMA16(ah[i], bl[j], acc[i][j]);
      #pragma unroll
      for (int i=0;i<4;i++) if (liA[i]){
        short8v al = *(const short8v*)(base + 8192 + offA[i]);
        #pragma unroll
        for (int j=0;j<4;j++) acc[i][j] = MFMA16(al, bh[j], acc[i][j]);
      }
      __builtin_amdgcn_s_setprio(0);
      if (more) TWRITE((t+1)&1)
      __syncthreads();
    }
#undef TLOAD
#undef TWRITE
  }

  // epilogue: split store + per-c-row sum-of-squares partials
  #pragma unroll
  for (int i=0;i<4;i++){
    #pragma unroll
    for (int r=0;r<4;r++){
      int grow = m0 + wr*64 + i*16 + lk*4 + r;     // c index
      float p = 0.f;
      size_t rowb = (size_t)bz*NC*NH + (size_t)grow*512 + n0 + wc*64 + lr;
      #pragma unroll
      for (int j=0;j<4;j++){
        float v = acc[i][j][r];
        p = fmaf(v,v,p);
        unsigned short h,lo2; fsplit(v,h,lo2);
        OutH[rowb + j*16] = h; OutL[rowb + j*16] = lo2;
      }
      p += __shfl_xor(p, 1, 64);
      p += __shfl_xor(p, 2, 64);
      p += __shfl_xor(p, 4, 64);
      p += __shfl_xor(p, 8, 64);
      if (lr == 0) parts[(((size_t)bz*NC) + grow)*8 + by*2 + wc] = p;
    }
  }
}

// ---------------- squash scale from partials ----------------
__global__ void __launch_bounds__(512) scale_kernel(const float* __restrict__ parts,
                                                    float* __restrict__ scale){
  int b = blockIdx.x, c = threadIdx.x;
  const float* p = parts + ((size_t)b*NC + c)*8;
  float m2 = ((p[0]+p[1])+(p[2]+p[3])) + ((p[4]+p[5])+(p[6]+p[7]));
  float sc = 0.0f;
  if (m2 > 0.0f) sc = (m2/(1.0f+m2)) / sqrtf(m2);
  scale[(size_t)b*NC + c] = sc;
}

// ---------------- orchestration ----------------
extern "C" void kernel_launch(void* const* d_in, const int* in_sizes, int n_in,
                              void* d_out, int out_size, void* d_ws, size_t ws_size,
                              hipStream_t stream) {
  const float* x    = (const float*)d_in[0];
  const float* adj  = (const float*)d_in[1];
  const float* W    = (const float*)d_in[2];
  const float* bias = (const float*)d_in[3];
  const unsigned char* mask = (const unsigned char*)d_in[4];
  float* out = (float*)d_out;                 // holds s (f32) and finally softmax(s)
  char* ws = (char*)d_ws;

  unsigned short* zh   = (unsigned short*)(ws);                 // 64 MB
  unsigned short* zl   = (unsigned short*)(ws + 67108864);      // 64 MB
  unsigned short* sth  = (unsigned short*)(ws + 134217728);     // 64 MB (aliases yh)
  unsigned short* stl  = (unsigned short*)(ws + 201326592);     // 64 MB (aliases yl)
  unsigned short* xnh  = (unsigned short*)(ws + 268435456);     // 16 MB
  unsigned short* xnl  = (unsigned short*)(ws + 285212672);     // 16 MB
  unsigned short* WTh  = (unsigned short*)(ws + 301989888);     // 0.5 MB
  unsigned short* WTl  = (unsigned short*)(ws + 302514176);     // 0.5 MB
  float* parts         = (float*)(ws + 303038464);              // 0.5 MB
  float* scalebuf      = (float*)(ws + 304087040);              // 64 KB
  int*   cnum          = (int*)(ws + 304152576);                // 128 B
  int*   lenbuf        = (int*)(ws + 304152704);                // 128 B
  unsigned short* yh = sth;
  unsigned short* yl = stl;

  counts_kernel<<<NB, 256, 0, stream>>>(mask, cnum, lenbuf);
  wsplit_kernel<<<dim3(16,16), 256, 0, stream>>>(W, WTh, WTl);
  spmm_kernel<<<ROWS, 256, 0, stream>>>(adj, x, yh, yl, lenbuf);
  // z = relu(y @ W + b): M=65536 N=512 K=512; 128x256 tiles, n-fastest
  gemmW_kernel<1><<<1024, 256, 0, stream>>>(
      yh, yl, WTh, WTl, zh, zl, nullptr, nullptr, nullptr, bias, nullptr,
      lenbuf, cnum, ND, 0, 0, 0);

  for (int it = 0; it < 3; ++it){
    // s~ = masked_softmax(s): iteration 0 fuses the threefry RNG (no s f32
    // round-trip); iterations 1,2 read s f32 written by the previous G3.
    if (it == 0)
      rngsm_kernel<<<ROWS/4, 256, 0, stream>>>(sth, stl, cnum);
    else
      softmax_kernel<true,false><<<ROWS/4, 256, 0, stream>>>(out, sth, stl, cnum);
    // xn[c][h] = sum_n s~[n][c] z[n][h]  (+ c-row sumsq partials)
    gemmT128_kernel<<<512, 256, 0, stream>>>(
        sth, stl, zh, zl, xnh, xnl, parts, lenbuf, cnum);
    scale_kernel<<<NB, 512, 0, stream>>>(parts, scalebuf);
    // s = (sth+stl) + scale[c] * (z @ xn^T): M=2048 N=512 K=512 per batch
    gemmW_kernel<2><<<1024, 256, 0, stream>>>(
        zh, zl, xnh, xnl, nullptr, nullptr, out, sth, stl, nullptr, scalebuf,
        lenbuf, cnum, NH, (long)NN*NH, (long)NC*NH, (long)NN*NC);
  }
  softmax_kernel<false,true><<<ROWS/4, 256, 0, stream>>>(out, nullptr, nullptr, cnum);
}